// Round 5
// baseline (376.604 us; speedup 1.0000x reference)
//
#include <hip/hip_runtime.h>

#define N_NODES 10000
#define N_EDGES 640000
#define IN_DIM  128
#define HID_DIM 256
#define OUT_DIM 128

#define MAXDEG  128   // deg ~ Binom(640k,1e-4): mean 64, P(>128) ~ 1e-11

#define NWIN      80
#define WIN_NODES 125              // 80 * 125 = 10000
#define K1_THREADS 512

typedef __attribute__((ext_vector_type(8))) short short8;
typedef __attribute__((ext_vector_type(4))) float float4v;
typedef unsigned short ushort_t;
typedef unsigned int uint_t;

__device__ inline ushort_t f2bf(float f) {
    uint_t u = __float_as_uint(f);
    u += 0x7fffu + ((u >> 16) & 1u);
    return (ushort_t)(u >> 16);
}
__device__ inline float bf_lo(uint_t u) { return __uint_as_float(u << 16); }
__device__ inline float bf_hi(uint_t u) { return __uint_as_float(u & 0xffff0000u); }

#define PREP_X   (N_NODES * IN_DIM)
#define PREP_W1  (HID_DIM * (2 * IN_DIM))
#define PREP_W2  (OUT_DIM * HID_DIM)
#define PREP_TOTAL (PREP_X + PREP_W1 + 2 * PREP_W2)   // 1,411,072

#define PREP_BLOCKS 1024
#define PREP_STRIDE (PREP_BLOCKS * K1_THREADS)

// ---------------------------------------------------------------------------
// K1: windowed LDS edge-binning (dense writes!) + prep.
// Blocks [0,NWIN): block w owns nodes [125w,125w+125). Scans the full dst
// array (L2-resident stream), bins in-window edges into a 32 KB LDS slot
// array via LDS-atomic cursors, then writes slots + cnt out DENSE.
// This kills round-4's 33 MB scattered-store write amplification (random 2 B
// stores dirtied 64 B lines across 8 non-coherent XCD L2s -> ~1 TB/s
// random-line writeback = 46 us).
// Blocks [NWIN,..): grid-stride prep (x->bf16, weights->transposed bf16).
// No memset dispatch needed: cnt written densely by bin blocks.
// ---------------------------------------------------------------------------
__global__ void __launch_bounds__(K1_THREADS)
bin_prep(const float* __restrict__ x, const int* __restrict__ ei,
         const float* __restrict__ W1_l, const float* __restrict__ W1_r,
         const float* __restrict__ W2_l, const float* __restrict__ W2_r,
         ushort_t* __restrict__ xb,  ushort_t* __restrict__ w1t,
         ushort_t* __restrict__ w2tl, ushort_t* __restrict__ w2tr,
         int* __restrict__ cnt, ushort_t* __restrict__ esrc2) {
    __shared__ alignas(16) ushort_t slots[WIN_NODES * MAXDEG];  // 32 KB
    __shared__ int lcnt[WIN_NODES];
    const int bid = blockIdx.x;
    const int tid = threadIdx.x;

    if (bid < NWIN) {
        const int lo = bid * WIN_NODES;
        for (int i = tid; i < WIN_NODES; i += K1_THREADS) lcnt[i] = 0;
        __syncthreads();
        const int* src = ei;
        const int4* d4 = (const int4*)(ei + N_EDGES);
        for (int t = tid; t < N_EDGES / 4; t += K1_THREADS) {
            int4 d = d4[t];
            int a, p;
            a = d.x - lo; if ((unsigned)a < (unsigned)WIN_NODES) {
                p = atomicAdd(&lcnt[a], 1);
                if (p < MAXDEG) slots[a * MAXDEG + p] = (ushort_t)src[t * 4 + 0];
            }
            a = d.y - lo; if ((unsigned)a < (unsigned)WIN_NODES) {
                p = atomicAdd(&lcnt[a], 1);
                if (p < MAXDEG) slots[a * MAXDEG + p] = (ushort_t)src[t * 4 + 1];
            }
            a = d.z - lo; if ((unsigned)a < (unsigned)WIN_NODES) {
                p = atomicAdd(&lcnt[a], 1);
                if (p < MAXDEG) slots[a * MAXDEG + p] = (ushort_t)src[t * 4 + 2];
            }
            a = d.w - lo; if ((unsigned)a < (unsigned)WIN_NODES) {
                p = atomicAdd(&lcnt[a], 1);
                if (p < MAXDEG) slots[a * MAXDEG + p] = (ushort_t)src[t * 4 + 3];
            }
        }
        __syncthreads();
        // dense write-out: 32 KB of full lines (garbage beyond deg is never read)
        uint4* dst4 = (uint4*)(esrc2 + lo * MAXDEG);
        const uint4* s4 = (const uint4*)slots;
        for (int i = tid; i < WIN_NODES * MAXDEG / 8; i += K1_THREADS)
            dst4[i] = s4[i];
        for (int i = tid; i < WIN_NODES; i += K1_THREADS)
            cnt[lo + i] = lcnt[i];
        return;
    }

    // ---- prep blocks ----
    const int gtid = (bid - NWIN) * K1_THREADS + tid;
    for (int i = gtid; i < PREP_TOTAL; i += PREP_STRIDE) {
        if (i < PREP_X) {
            xb[i] = f2bf(x[i]);
        } else if (i < PREP_X + PREP_W1) {
            int j = i - PREP_X;
            int n = j >> 8, k = j & 255;          // w1t[n][k], n in [0,256)
            float v = (k < 128) ? W1_l[k * HID_DIM + n] : W1_r[(k - 128) * HID_DIM + n];
            w1t[j] = f2bf(v);
        } else if (i < PREP_X + PREP_W1 + PREP_W2) {
            int j = i - (PREP_X + PREP_W1);
            int n = j >> 8, k = j & 255;
            w2tl[j] = f2bf(W2_l[k * OUT_DIM + n]);
        } else {
            int j = i - (PREP_X + PREP_W1 + PREP_W2);
            int n = j >> 8, k = j & 255;
            w2tr[j] = f2bf(W2_r[k * OUT_DIM + n]);
        }
    }
}

// ---------------------------------------------------------------------------
// K2: fused gather-mean + GEMM layers 1+2 per 16-node tile. 625 blocks x 512.
//   gather: wave w gathers nodes wrow+2w, wrow+2w+1 into swizzled LDS aggl.
//           idx rows staged in LDS (kills the per-lane scalar 2 B load chain);
//           4 row-loads in flight.
//   phase 1: wave w computes h cols [32w,32w+32) = relu([agg|x]@W1+b1) -> hl.
//   phase 2: waves 0-3 -> Pb = h@W2_l (bf16); waves 4-7 -> Rf = h@W2_r (f32).
// Swizzles (G4): byte ^= ((row&7)<<4), same involution write & read.
// A-frag: A[m=lane&15][k=q*8+j]; B-frag: Wt[n][k]; C/D: col=lane&15,
// row=q*4+reg (m89-verified layouts).
// ---------------------------------------------------------------------------
__global__ void __launch_bounds__(512)
gather_gemm(const ushort_t* __restrict__ xb, const int* __restrict__ cnt,
            const ushort_t* __restrict__ esrc2, const ushort_t* __restrict__ w1t,
            const float* __restrict__ b1, const ushort_t* __restrict__ w2tl,
            const ushort_t* __restrict__ w2tr,
            ushort_t* __restrict__ Pb, float* __restrict__ Rf) {
    __shared__ alignas(16) ushort_t aggl[16 * 128];       // 4 KB, swizzled
    __shared__ alignas(16) ushort_t hl[16 * 256];         // 8 KB, swizzled
    __shared__ alignas(16) ushort_t sidx[8][2][MAXDEG];   // 4 KB idx staging
    const int wrow = blockIdx.x * 16;
    const int w = threadIdx.x >> 6;               // wave 0..7
    const int lane = threadIdx.x & 63;

    // stage this wave's two idx rows (2 x 256 B) via uint4
    if (lane < 32) {
        int nd = lane >> 4, i = lane & 15;
        ((uint4*)sidx[w][nd])[i] =
            ((const uint4*)(esrc2 + (wrow + w * 2 + nd) * MAXDEG))[i];
    }

    // ---- gather 2 nodes per wave into aggl ----
    {
        const uint4* f = (const uint4*)xb;        // 16 uint4 per 256 B row
        const int g = lane >> 4;                  // slot group 0..3
        const int c = lane & 15;                  // 16 B column
        for (int i = 0; i < 2; ++i) {
            const int row = w * 2 + i;
            const int n = wrow + row;
            const int deg = min(cnt[n], MAXDEG);
            const ushort_t* idx = sidx[w][i];
            float a0=0,a1=0,a2=0,a3=0,a4=0,a5=0,a6=0,a7=0;
            int e = g;
            for (; e + 12 < deg; e += 16) {        // 4 rows in flight per group
                uint4 u0 = f[(int)idx[e]      * 16 + c];
                uint4 u1 = f[(int)idx[e + 4]  * 16 + c];
                uint4 u2 = f[(int)idx[e + 8]  * 16 + c];
                uint4 u3 = f[(int)idx[e + 12] * 16 + c];
                a0 += bf_lo(u0.x) + bf_lo(u1.x) + bf_lo(u2.x) + bf_lo(u3.x);
                a1 += bf_hi(u0.x) + bf_hi(u1.x) + bf_hi(u2.x) + bf_hi(u3.x);
                a2 += bf_lo(u0.y) + bf_lo(u1.y) + bf_lo(u2.y) + bf_lo(u3.y);
                a3 += bf_hi(u0.y) + bf_hi(u1.y) + bf_hi(u2.y) + bf_hi(u3.y);
                a4 += bf_lo(u0.z) + bf_lo(u1.z) + bf_lo(u2.z) + bf_lo(u3.z);
                a5 += bf_hi(u0.z) + bf_hi(u1.z) + bf_hi(u2.z) + bf_hi(u3.z);
                a6 += bf_lo(u0.w) + bf_lo(u1.w) + bf_lo(u2.w) + bf_lo(u3.w);
                a7 += bf_hi(u0.w) + bf_hi(u1.w) + bf_hi(u2.w) + bf_hi(u3.w);
            }
            for (; e < deg; e += 4) {
                uint4 u = f[(int)idx[e] * 16 + c];
                a0 += bf_lo(u.x); a1 += bf_hi(u.x);
                a2 += bf_lo(u.y); a3 += bf_hi(u.y);
                a4 += bf_lo(u.z); a5 += bf_hi(u.z);
                a6 += bf_lo(u.w); a7 += bf_hi(u.w);
            }
#pragma unroll
            for (int off = 32; off >= 16; off >>= 1) {
                a0 += __shfl_down(a0, off); a1 += __shfl_down(a1, off);
                a2 += __shfl_down(a2, off); a3 += __shfl_down(a3, off);
                a4 += __shfl_down(a4, off); a5 += __shfl_down(a5, off);
                a6 += __shfl_down(a6, off); a7 += __shfl_down(a7, off);
            }
            if (g == 0) {
                const float dinv = (deg > 0) ? 1.0f / (float)deg : 0.0f;
                uint4 o;
                o.x = (uint_t)f2bf(a0 * dinv) | ((uint_t)f2bf(a1 * dinv) << 16);
                o.y = (uint_t)f2bf(a2 * dinv) | ((uint_t)f2bf(a3 * dinv) << 16);
                o.z = (uint_t)f2bf(a4 * dinv) | ((uint_t)f2bf(a5 * dinv) << 16);
                o.w = (uint_t)f2bf(a6 * dinv) | ((uint_t)f2bf(a7 * dinv) << 16);
                int byte = (row * 256 + c * 16) ^ ((row & 7) << 4);
                *(uint4*)((char*)aggl + byte) = o;
            }
        }
    }
    __syncthreads();

    // ---- phase 1: h cols [32w, 32w+32) ----
    const int m = lane & 15, q = lane >> 4;
    {
        float4v acc[2];
#pragma unroll
        for (int t = 0; t < 2; ++t) acc[t] = (float4v){0.f, 0.f, 0.f, 0.f};
        const ushort_t* arow_x = xb + (wrow + m) * IN_DIM + q * 8;
        const ushort_t* bbase1 = w1t + (w * 32 + m) * 256 + q * 8;
#pragma unroll
        for (int s = 0; s < 8; ++s) {
            short8 a;
            if (s < 4) {
                int byte = (m * 256 + q * 16 + s * 64) ^ ((m & 7) << 4);
                a = *(const short8*)((const char*)aggl + byte);
            } else {
                a = *(const short8*)(arow_x + (s - 4) * 32);
            }
#pragma unroll
            for (int t = 0; t < 2; ++t) {
                short8 b = *(const short8*)(bbase1 + (t * 16) * 256 + s * 32);
                acc[t] = __builtin_amdgcn_mfma_f32_16x16x32_bf16(a, b, acc[t], 0, 0, 0);
            }
        }
#pragma unroll
        for (int t = 0; t < 2; ++t) {
            int col = w * 32 + t * 16 + m;
            float bv = b1[col];
#pragma unroll
            for (int r = 0; r < 4; ++r) {
                int row = q * 4 + r;
                float v = fmaxf(acc[t][r] + bv, 0.0f);
                int byte = (row * 512 + col * 2) ^ ((row & 7) << 4);
                *(ushort_t*)((char*)hl + byte) = f2bf(v);
            }
        }
    }
    __syncthreads();

    // ---- phase 2: waves 0-3 -> P, waves 4-7 -> R ----
    {
        const int isP = (w < 4);
        const int cb = (w & 3) * 32;
        const ushort_t* wt = isP ? w2tl : w2tr;
        float4v acc2[2];
#pragma unroll
        for (int t = 0; t < 2; ++t) acc2[t] = (float4v){0.f, 0.f, 0.f, 0.f};
        const ushort_t* bbase2 = wt + (cb + m) * 256 + q * 8;
#pragma unroll
        for (int s = 0; s < 8; ++s) {
            int byte = (m * 512 + q * 16 + s * 64) ^ ((m & 7) << 4);
            short8 a = *(const short8*)((const char*)hl + byte);
#pragma unroll
            for (int t = 0; t < 2; ++t) {
                short8 b = *(const short8*)(bbase2 + (t * 16) * 256 + s * 32);
                acc2[t] = __builtin_amdgcn_mfma_f32_16x16x32_bf16(a, b, acc2[t], 0, 0, 0);
            }
        }
        if (isP) {
#pragma unroll
            for (int t = 0; t < 2; ++t) {
                int col = cb + t * 16 + m;
#pragma unroll
                for (int r = 0; r < 4; ++r)
                    Pb[(wrow + q * 4 + r) * OUT_DIM + col] = f2bf(acc2[t][r]);
            }
        } else {
#pragma unroll
            for (int t = 0; t < 2; ++t) {
                int col = cb + t * 16 + m;
#pragma unroll
                for (int r = 0; r < 4; ++r)
                    Rf[(wrow + q * 4 + r) * OUT_DIM + col] = acc2[t][r];
            }
        }
    }
}

// ---------------------------------------------------------------------------
// K3: final gather + epilogue: out[n][:] = mean_e P[esrc[e]][:] + R[n][:] + b2
// One 64-thread block per node; idx staged in LDS; 4 rows in flight.
// ---------------------------------------------------------------------------
__global__ void gather_final(const ushort_t* __restrict__ Pb,
                             const int* __restrict__ degp,
                             const ushort_t* __restrict__ esrc2,
                             const float* __restrict__ Rf,
                             const float* __restrict__ b2,
                             float* __restrict__ out) {
    __shared__ alignas(16) ushort_t sidx[MAXDEG];
    const uint4* f = (const uint4*)Pb;            // 16 uint4 per row
    const int n = blockIdx.x;
    const int g = threadIdx.x >> 4;
    const int c = threadIdx.x & 15;
    const int deg = min(degp[n], MAXDEG);

    if (threadIdx.x < 16)
        ((uint4*)sidx)[threadIdx.x] = ((const uint4*)(esrc2 + n * MAXDEG))[threadIdx.x];
    __syncthreads();

    float a0=0,a1=0,a2=0,a3=0,a4=0,a5=0,a6=0,a7=0;
    int e = g;
    for (; e + 12 < deg; e += 16) {
        uint4 u0 = f[(int)sidx[e]      * 16 + c];
        uint4 u1 = f[(int)sidx[e + 4]  * 16 + c];
        uint4 u2 = f[(int)sidx[e + 8]  * 16 + c];
        uint4 u3 = f[(int)sidx[e + 12] * 16 + c];
        a0 += bf_lo(u0.x) + bf_lo(u1.x) + bf_lo(u2.x) + bf_lo(u3.x);
        a1 += bf_hi(u0.x) + bf_hi(u1.x) + bf_hi(u2.x) + bf_hi(u3.x);
        a2 += bf_lo(u0.y) + bf_lo(u1.y) + bf_lo(u2.y) + bf_lo(u3.y);
        a3 += bf_hi(u0.y) + bf_hi(u1.y) + bf_hi(u2.y) + bf_hi(u3.y);
        a4 += bf_lo(u0.z) + bf_lo(u1.z) + bf_lo(u2.z) + bf_lo(u3.z);
        a5 += bf_hi(u0.z) + bf_hi(u1.z) + bf_hi(u2.z) + bf_hi(u3.z);
        a6 += bf_lo(u0.w) + bf_lo(u1.w) + bf_lo(u2.w) + bf_lo(u3.w);
        a7 += bf_hi(u0.w) + bf_hi(u1.w) + bf_hi(u2.w) + bf_hi(u3.w);
    }
    for (; e < deg; e += 4) {
        uint4 u = f[(int)sidx[e] * 16 + c];
        a0 += bf_lo(u.x); a1 += bf_hi(u.x);
        a2 += bf_lo(u.y); a3 += bf_hi(u.y);
        a4 += bf_lo(u.z); a5 += bf_hi(u.z);
        a6 += bf_lo(u.w); a7 += bf_hi(u.w);
    }
#pragma unroll
    for (int off = 32; off >= 16; off >>= 1) {
        a0 += __shfl_down(a0, off); a1 += __shfl_down(a1, off);
        a2 += __shfl_down(a2, off); a3 += __shfl_down(a3, off);
        a4 += __shfl_down(a4, off); a5 += __shfl_down(a5, off);
        a6 += __shfl_down(a6, off); a7 += __shfl_down(a7, off);
    }
    if (g == 0) {
        const float dinv = (deg > 0) ? 1.0f / (float)deg : 0.0f;
        const int base = n * OUT_DIM + c * 8;
        float4 r0 = *(const float4*)(Rf + base);
        float4 r1 = *(const float4*)(Rf + base + 4);
        float4 o0, o1;
        o0.x = a0 * dinv + r0.x + b2[c * 8 + 0];
        o0.y = a1 * dinv + r0.y + b2[c * 8 + 1];
        o0.z = a2 * dinv + r0.z + b2[c * 8 + 2];
        o0.w = a3 * dinv + r0.w + b2[c * 8 + 3];
        o1.x = a4 * dinv + r1.x + b2[c * 8 + 4];
        o1.y = a5 * dinv + r1.y + b2[c * 8 + 5];
        o1.z = a6 * dinv + r1.z + b2[c * 8 + 6];
        o1.w = a7 * dinv + r1.w + b2[c * 8 + 7];
        *(float4*)(out + base)     = o0;
        *(float4*)(out + base + 4) = o1;
    }
}

// ---------------------------------------------------------------------------
// Launch: 3 kernels, no memset (bin blocks write cnt densely).
// ---------------------------------------------------------------------------
extern "C" void kernel_launch(void* const* d_in, const int* in_sizes, int n_in,
                              void* d_out, int out_size, void* d_ws, size_t ws_size,
                              hipStream_t stream) {
    const float* x    = (const float*)d_in[0];
    const int*   ei   = (const int*)  d_in[1];
    const float* W1_l = (const float*)d_in[2];
    const float* b1   = (const float*)d_in[3];
    const float* W1_r = (const float*)d_in[4];
    const float* W2_l = (const float*)d_in[5];
    const float* b2   = (const float*)d_in[6];
    const float* W2_r = (const float*)d_in[7];
    float* out = (float*)d_out;

    // ---- workspace layout (byte offsets, all 16 B-aligned) ----
    char* w = (char*)d_ws;
    int*      cnt   = (int*)     (w + 0);          //    40,000 B (reserve 64 KB)
    ushort_t* esrc2 = (ushort_t*)(w + 65536);      // 2,560,000 B
    ushort_t* xb    = (ushort_t*)(w + 2625536);    // 2,560,000 B
    ushort_t* Pb    = (ushort_t*)(w + 5185536);    // 2,560,000 B
    ushort_t* w1t   = (ushort_t*)(w + 7745536);    //   131,072 B
    ushort_t* w2tl  = (ushort_t*)(w + 7876608);    //    65,536 B
    ushort_t* w2tr  = (ushort_t*)(w + 7942144);    //    65,536 B
    float*    Rf    = (float*)   (w + 8007680);    // 5,120,000 B -> ends 13,127,680

    bin_prep<<<NWIN + PREP_BLOCKS, K1_THREADS, 0, stream>>>(
        x, ei, W1_l, W1_r, W2_l, W2_r, xb, w1t, w2tl, w2tr, cnt, esrc2);
    gather_gemm<<<625, 512, 0, stream>>>(xb, cnt, esrc2, w1t, b1, w2tl, w2tr, Pb, Rf);
    gather_final<<<N_NODES, 64, 0, stream>>>(Pb, cnt, esrc2, Rf, b2, out);
}

// Round 6
// 144.366 us; speedup vs baseline: 2.6087x; 2.6087x over previous
//
#include <hip/hip_runtime.h>

#define N_NODES 10000
#define N_EDGES 640000
#define IN_DIM  128
#define HID_DIM 256
#define OUT_DIM 128

#define MAXDEG  128   // deg ~ Binom(640k,1e-4): mean 64, P(>128) ~ 1e-11

#define NWIN      80
#define WIN_NODES 125              // 80 * 125 = 10000
#define NPART     8                // edge partitions per window
#define EDGES_PER_PART (N_EDGES / NPART)     // 80,000
#define CAP       48               // per-(node,part) slot cap: lambda=8, P(>48)~0
#define K1_THREADS 512

typedef __attribute__((ext_vector_type(8))) short short8;
typedef __attribute__((ext_vector_type(4))) float float4v;
typedef unsigned short ushort_t;
typedef unsigned int uint_t;

__device__ inline ushort_t f2bf(float f) {
    uint_t u = __float_as_uint(f);
    u += 0x7fffu + ((u >> 16) & 1u);
    return (ushort_t)(u >> 16);
}
__device__ inline float bf_lo(uint_t u) { return __uint_as_float(u << 16); }
__device__ inline float bf_hi(uint_t u) { return __uint_as_float(u & 0xffff0000u); }

#define PREP_X   (N_NODES * IN_DIM)
#define PREP_W1  (HID_DIM * (2 * IN_DIM))
#define PREP_W2  (OUT_DIM * HID_DIM)
#define PREP_TOTAL (PREP_X + PREP_W1 + 2 * PREP_W2)   // 1,411,072

#define BIN_BLOCKS (NWIN * NPART)            // 640
#define PREP_BLOCKS 1024
#define PREP_STRIDE (PREP_BLOCKS * K1_THREADS)

// ---------------------------------------------------------------------------
// K1: (window x edge-part) LDS binning + global slot reservation + prep.
// vs round 5 (80 blocks, 265 us, 2000 cy/iter serial chain):
//   - 640 bin blocks (8 edge-partitions per window): 8x less serial depth,
//     8x more TLP.
//   - src+dst loaded as UNCONDITIONAL paired int4 (in flight together);
//     branch bodies are pure LDS ops — no global load on the dependent path.
//   - slot bases via one global atomicAdd(cnt[n], k) per (node,part);
//     copies land as ~16 B contiguous runs (dense-ish writes, keeps round 5's
//     WRITE_SIZE win; round 4's random 2 B stores cost 33 MB writeback).
// ---------------------------------------------------------------------------
__global__ void __launch_bounds__(K1_THREADS)
bin_prep(const float* __restrict__ x, const int* __restrict__ ei,
         const float* __restrict__ W1_l, const float* __restrict__ W1_r,
         const float* __restrict__ W2_l, const float* __restrict__ W2_r,
         ushort_t* __restrict__ xb,  ushort_t* __restrict__ w1t,
         ushort_t* __restrict__ w2tl, ushort_t* __restrict__ w2tr,
         int* __restrict__ cnt, ushort_t* __restrict__ esrc2) {
    __shared__ alignas(16) ushort_t slots[WIN_NODES * CAP];   // 12,000 B
    __shared__ int lcnt[WIN_NODES];
    __shared__ int lbase[WIN_NODES];
    const int bid = blockIdx.x;
    const int tid = threadIdx.x;

    if (bid < BIN_BLOCKS) {
        const int win  = bid >> 3;           // 0..79
        const int part = bid & (NPART - 1);  // 0..7
        const int lo   = win * WIN_NODES;
        if (tid < WIN_NODES) lcnt[tid] = 0;
        __syncthreads();

        const int4* s4 = (const int4*)ei + part * (EDGES_PER_PART / 4);
        const int4* d4 = (const int4*)(ei + N_EDGES) + part * (EDGES_PER_PART / 4);
        for (int t = tid; t < EDGES_PER_PART / 4; t += K1_THREADS) {
            int4 d = d4[t];
            int4 s = s4[t];                  // unconditional: overlaps with d load
            int a, p;
            a = d.x - lo; if ((unsigned)a < (unsigned)WIN_NODES) {
                p = atomicAdd(&lcnt[a], 1); if (p < CAP) slots[a * CAP + p] = (ushort_t)s.x;
            }
            a = d.y - lo; if ((unsigned)a < (unsigned)WIN_NODES) {
                p = atomicAdd(&lcnt[a], 1); if (p < CAP) slots[a * CAP + p] = (ushort_t)s.y;
            }
            a = d.z - lo; if ((unsigned)a < (unsigned)WIN_NODES) {
                p = atomicAdd(&lcnt[a], 1); if (p < CAP) slots[a * CAP + p] = (ushort_t)s.z;
            }
            a = d.w - lo; if ((unsigned)a < (unsigned)WIN_NODES) {
                p = atomicAdd(&lcnt[a], 1); if (p < CAP) slots[a * CAP + p] = (ushort_t)s.w;
            }
        }
        __syncthreads();
        // reserve slot ranges in the global per-node lists
        for (int i = tid; i < WIN_NODES; i += K1_THREADS)
            lbase[i] = atomicAdd(&cnt[lo + i], min(lcnt[i], CAP));
        __syncthreads();
        // copy out: thread per (node, slot); contiguous ~16 B runs per node
        for (int i = tid; i < WIN_NODES * CAP; i += K1_THREADS) {
            int node = i / CAP, slot = i - node * CAP;
            if (slot < min(lcnt[node], CAP)) {
                int pos = lbase[node] + slot;
                if (pos < MAXDEG) esrc2[(lo + node) * MAXDEG + pos] = slots[i];
            }
        }
        return;
    }

    // ---- prep blocks ----
    const int gtid = (bid - BIN_BLOCKS) * K1_THREADS + tid;
    for (int i = gtid; i < PREP_TOTAL; i += PREP_STRIDE) {
        if (i < PREP_X) {
            xb[i] = f2bf(x[i]);
        } else if (i < PREP_X + PREP_W1) {
            int j = i - PREP_X;
            int n = j >> 8, k = j & 255;          // w1t[n][k], n in [0,256)
            float v = (k < 128) ? W1_l[k * HID_DIM + n] : W1_r[(k - 128) * HID_DIM + n];
            w1t[j] = f2bf(v);
        } else if (i < PREP_X + PREP_W1 + PREP_W2) {
            int j = i - (PREP_X + PREP_W1);
            int n = j >> 8, k = j & 255;
            w2tl[j] = f2bf(W2_l[k * OUT_DIM + n]);
        } else {
            int j = i - (PREP_X + PREP_W1 + PREP_W2);
            int n = j >> 8, k = j & 255;
            w2tr[j] = f2bf(W2_r[k * OUT_DIM + n]);
        }
    }
}

// ---------------------------------------------------------------------------
// K2: fused gather-mean + GEMM layers 1+2 per 16-node tile. 625 blocks x 512.
//   gather: wave w gathers nodes wrow+2w, wrow+2w+1 into swizzled LDS aggl.
//           idx rows staged in LDS; 4 row-loads in flight.
//   phase 1: wave w computes h cols [32w,32w+32) = relu([agg|x]@W1+b1) -> hl.
//   phase 2: waves 0-3 -> Pb = h@W2_l (bf16); waves 4-7 -> Rf = h@W2_r (f32).
// Swizzles (G4): byte ^= ((row&7)<<4), same involution write & read.
// A-frag: A[m=lane&15][k=q*8+j]; B-frag: Wt[n][k]; C/D: col=lane&15,
// row=q*4+reg (m89-verified layouts).
// ---------------------------------------------------------------------------
__global__ void __launch_bounds__(512)
gather_gemm(const ushort_t* __restrict__ xb, const int* __restrict__ cnt,
            const ushort_t* __restrict__ esrc2, const ushort_t* __restrict__ w1t,
            const float* __restrict__ b1, const ushort_t* __restrict__ w2tl,
            const ushort_t* __restrict__ w2tr,
            ushort_t* __restrict__ Pb, float* __restrict__ Rf) {
    __shared__ alignas(16) ushort_t aggl[16 * 128];       // 4 KB, swizzled
    __shared__ alignas(16) ushort_t hl[16 * 256];         // 8 KB, swizzled
    __shared__ alignas(16) ushort_t sidx[8][2][MAXDEG];   // 4 KB idx staging
    const int wrow = blockIdx.x * 16;
    const int w = threadIdx.x >> 6;               // wave 0..7
    const int lane = threadIdx.x & 63;

    // stage this wave's two idx rows (2 x 256 B) via uint4
    if (lane < 32) {
        int nd = lane >> 4, i = lane & 15;
        ((uint4*)sidx[w][nd])[i] =
            ((const uint4*)(esrc2 + (wrow + w * 2 + nd) * MAXDEG))[i];
    }

    // ---- gather 2 nodes per wave into aggl ----
    {
        const uint4* f = (const uint4*)xb;        // 16 uint4 per 256 B row
        const int g = lane >> 4;                  // slot group 0..3
        const int c = lane & 15;                  // 16 B column
        for (int i = 0; i < 2; ++i) {
            const int row = w * 2 + i;
            const int n = wrow + row;
            const int deg = min(cnt[n], MAXDEG);
            const ushort_t* idx = sidx[w][i];
            float a0=0,a1=0,a2=0,a3=0,a4=0,a5=0,a6=0,a7=0;
            int e = g;
            for (; e + 12 < deg; e += 16) {        // 4 rows in flight per group
                uint4 u0 = f[(int)idx[e]      * 16 + c];
                uint4 u1 = f[(int)idx[e + 4]  * 16 + c];
                uint4 u2 = f[(int)idx[e + 8]  * 16 + c];
                uint4 u3 = f[(int)idx[e + 12] * 16 + c];
                a0 += bf_lo(u0.x) + bf_lo(u1.x) + bf_lo(u2.x) + bf_lo(u3.x);
                a1 += bf_hi(u0.x) + bf_hi(u1.x) + bf_hi(u2.x) + bf_hi(u3.x);
                a2 += bf_lo(u0.y) + bf_lo(u1.y) + bf_lo(u2.y) + bf_lo(u3.y);
                a3 += bf_hi(u0.y) + bf_hi(u1.y) + bf_hi(u2.y) + bf_hi(u3.y);
                a4 += bf_lo(u0.z) + bf_lo(u1.z) + bf_lo(u2.z) + bf_lo(u3.z);
                a5 += bf_hi(u0.z) + bf_hi(u1.z) + bf_hi(u2.z) + bf_hi(u3.z);
                a6 += bf_lo(u0.w) + bf_lo(u1.w) + bf_lo(u2.w) + bf_lo(u3.w);
                a7 += bf_hi(u0.w) + bf_hi(u1.w) + bf_hi(u2.w) + bf_hi(u3.w);
            }
            for (; e < deg; e += 4) {
                uint4 u = f[(int)idx[e] * 16 + c];
                a0 += bf_lo(u.x); a1 += bf_hi(u.x);
                a2 += bf_lo(u.y); a3 += bf_hi(u.y);
                a4 += bf_lo(u.z); a5 += bf_hi(u.z);
                a6 += bf_lo(u.w); a7 += bf_hi(u.w);
            }
#pragma unroll
            for (int off = 32; off >= 16; off >>= 1) {
                a0 += __shfl_down(a0, off); a1 += __shfl_down(a1, off);
                a2 += __shfl_down(a2, off); a3 += __shfl_down(a3, off);
                a4 += __shfl_down(a4, off); a5 += __shfl_down(a5, off);
                a6 += __shfl_down(a6, off); a7 += __shfl_down(a7, off);
            }
            if (g == 0) {
                const float dinv = (deg > 0) ? 1.0f / (float)deg : 0.0f;
                uint4 o;
                o.x = (uint_t)f2bf(a0 * dinv) | ((uint_t)f2bf(a1 * dinv) << 16);
                o.y = (uint_t)f2bf(a2 * dinv) | ((uint_t)f2bf(a3 * dinv) << 16);
                o.z = (uint_t)f2bf(a4 * dinv) | ((uint_t)f2bf(a5 * dinv) << 16);
                o.w = (uint_t)f2bf(a6 * dinv) | ((uint_t)f2bf(a7 * dinv) << 16);
                int byte = (row * 256 + c * 16) ^ ((row & 7) << 4);
                *(uint4*)((char*)aggl + byte) = o;
            }
        }
    }
    __syncthreads();

    // ---- phase 1: h cols [32w, 32w+32) ----
    const int m = lane & 15, q = lane >> 4;
    {
        float4v acc[2];
#pragma unroll
        for (int t = 0; t < 2; ++t) acc[t] = (float4v){0.f, 0.f, 0.f, 0.f};
        const ushort_t* arow_x = xb + (wrow + m) * IN_DIM + q * 8;
        const ushort_t* bbase1 = w1t + (w * 32 + m) * 256 + q * 8;
#pragma unroll
        for (int s = 0; s < 8; ++s) {
            short8 a;
            if (s < 4) {
                int byte = (m * 256 + q * 16 + s * 64) ^ ((m & 7) << 4);
                a = *(const short8*)((const char*)aggl + byte);
            } else {
                a = *(const short8*)(arow_x + (s - 4) * 32);
            }
#pragma unroll
            for (int t = 0; t < 2; ++t) {
                short8 b = *(const short8*)(bbase1 + (t * 16) * 256 + s * 32);
                acc[t] = __builtin_amdgcn_mfma_f32_16x16x32_bf16(a, b, acc[t], 0, 0, 0);
            }
        }
#pragma unroll
        for (int t = 0; t < 2; ++t) {
            int col = w * 32 + t * 16 + m;
            float bv = b1[col];
#pragma unroll
            for (int r = 0; r < 4; ++r) {
                int row = q * 4 + r;
                float v = fmaxf(acc[t][r] + bv, 0.0f);
                int byte = (row * 512 + col * 2) ^ ((row & 7) << 4);
                *(ushort_t*)((char*)hl + byte) = f2bf(v);
            }
        }
    }
    __syncthreads();

    // ---- phase 2: waves 0-3 -> P, waves 4-7 -> R ----
    {
        const int isP = (w < 4);
        const int cb = (w & 3) * 32;
        const ushort_t* wt = isP ? w2tl : w2tr;
        float4v acc2[2];
#pragma unroll
        for (int t = 0; t < 2; ++t) acc2[t] = (float4v){0.f, 0.f, 0.f, 0.f};
        const ushort_t* bbase2 = wt + (cb + m) * 256 + q * 8;
#pragma unroll
        for (int s = 0; s < 8; ++s) {
            int byte = (m * 512 + q * 16 + s * 64) ^ ((m & 7) << 4);
            short8 a = *(const short8*)((const char*)hl + byte);
#pragma unroll
            for (int t = 0; t < 2; ++t) {
                short8 b = *(const short8*)(bbase2 + (t * 16) * 256 + s * 32);
                acc2[t] = __builtin_amdgcn_mfma_f32_16x16x32_bf16(a, b, acc2[t], 0, 0, 0);
            }
        }
        if (isP) {
#pragma unroll
            for (int t = 0; t < 2; ++t) {
                int col = cb + t * 16 + m;
#pragma unroll
                for (int r = 0; r < 4; ++r)
                    Pb[(wrow + q * 4 + r) * OUT_DIM + col] = f2bf(acc2[t][r]);
            }
        } else {
#pragma unroll
            for (int t = 0; t < 2; ++t) {
                int col = cb + t * 16 + m;
#pragma unroll
                for (int r = 0; r < 4; ++r)
                    Rf[(wrow + q * 4 + r) * OUT_DIM + col] = acc2[t][r];
            }
        }
    }
}

// ---------------------------------------------------------------------------
// K3: final gather + epilogue: out[n][:] = mean_e P[esrc[e]][:] + R[n][:] + b2
// One 64-thread block per node; idx staged in LDS; 4 rows in flight.
// ---------------------------------------------------------------------------
__global__ void gather_final(const ushort_t* __restrict__ Pb,
                             const int* __restrict__ degp,
                             const ushort_t* __restrict__ esrc2,
                             const float* __restrict__ Rf,
                             const float* __restrict__ b2,
                             float* __restrict__ out) {
    __shared__ alignas(16) ushort_t sidx[MAXDEG];
    const uint4* f = (const uint4*)Pb;            // 16 uint4 per row
    const int n = blockIdx.x;
    const int g = threadIdx.x >> 4;
    const int c = threadIdx.x & 15;
    const int deg = min(degp[n], MAXDEG);

    if (threadIdx.x < 16)
        ((uint4*)sidx)[threadIdx.x] = ((const uint4*)(esrc2 + n * MAXDEG))[threadIdx.x];
    __syncthreads();

    float a0=0,a1=0,a2=0,a3=0,a4=0,a5=0,a6=0,a7=0;
    int e = g;
    for (; e + 12 < deg; e += 16) {
        uint4 u0 = f[(int)sidx[e]      * 16 + c];
        uint4 u1 = f[(int)sidx[e + 4]  * 16 + c];
        uint4 u2 = f[(int)sidx[e + 8]  * 16 + c];
        uint4 u3 = f[(int)sidx[e + 12] * 16 + c];
        a0 += bf_lo(u0.x) + bf_lo(u1.x) + bf_lo(u2.x) + bf_lo(u3.x);
        a1 += bf_hi(u0.x) + bf_hi(u1.x) + bf_hi(u2.x) + bf_hi(u3.x);
        a2 += bf_lo(u0.y) + bf_lo(u1.y) + bf_lo(u2.y) + bf_lo(u3.y);
        a3 += bf_hi(u0.y) + bf_hi(u1.y) + bf_hi(u2.y) + bf_hi(u3.y);
        a4 += bf_lo(u0.z) + bf_lo(u1.z) + bf_lo(u2.z) + bf_lo(u3.z);
        a5 += bf_hi(u0.z) + bf_hi(u1.z) + bf_hi(u2.z) + bf_hi(u3.z);
        a6 += bf_lo(u0.w) + bf_lo(u1.w) + bf_lo(u2.w) + bf_lo(u3.w);
        a7 += bf_hi(u0.w) + bf_hi(u1.w) + bf_hi(u2.w) + bf_hi(u3.w);
    }
    for (; e < deg; e += 4) {
        uint4 u = f[(int)sidx[e] * 16 + c];
        a0 += bf_lo(u.x); a1 += bf_hi(u.x);
        a2 += bf_lo(u.y); a3 += bf_hi(u.y);
        a4 += bf_lo(u.z); a5 += bf_hi(u.z);
        a6 += bf_lo(u.w); a7 += bf_hi(u.w);
    }
#pragma unroll
    for (int off = 32; off >= 16; off >>= 1) {
        a0 += __shfl_down(a0, off); a1 += __shfl_down(a1, off);
        a2 += __shfl_down(a2, off); a3 += __shfl_down(a3, off);
        a4 += __shfl_down(a4, off); a5 += __shfl_down(a5, off);
        a6 += __shfl_down(a6, off); a7 += __shfl_down(a7, off);
    }
    if (g == 0) {
        const float dinv = (deg > 0) ? 1.0f / (float)deg : 0.0f;
        const int base = n * OUT_DIM + c * 8;
        float4 r0 = *(const float4*)(Rf + base);
        float4 r1 = *(const float4*)(Rf + base + 4);
        float4 o0, o1;
        o0.x = a0 * dinv + r0.x + b2[c * 8 + 0];
        o0.y = a1 * dinv + r0.y + b2[c * 8 + 1];
        o0.z = a2 * dinv + r0.z + b2[c * 8 + 2];
        o0.w = a3 * dinv + r0.w + b2[c * 8 + 3];
        o1.x = a4 * dinv + r1.x + b2[c * 8 + 4];
        o1.y = a5 * dinv + r1.y + b2[c * 8 + 5];
        o1.z = a6 * dinv + r1.z + b2[c * 8 + 6];
        o1.w = a7 * dinv + r1.w + b2[c * 8 + 7];
        *(float4*)(out + base)     = o0;
        *(float4*)(out + base + 4) = o1;
    }
}

// ---------------------------------------------------------------------------
// Launch: memset (cnt, needed for atomic slot reservation) + 3 kernels.
// ---------------------------------------------------------------------------
extern "C" void kernel_launch(void* const* d_in, const int* in_sizes, int n_in,
                              void* d_out, int out_size, void* d_ws, size_t ws_size,
                              hipStream_t stream) {
    const float* x    = (const float*)d_in[0];
    const int*   ei   = (const int*)  d_in[1];
    const float* W1_l = (const float*)d_in[2];
    const float* b1   = (const float*)d_in[3];
    const float* W1_r = (const float*)d_in[4];
    const float* W2_l = (const float*)d_in[5];
    const float* b2   = (const float*)d_in[6];
    const float* W2_r = (const float*)d_in[7];
    float* out = (float*)d_out;

    // ---- workspace layout (byte offsets, all 16 B-aligned) ----
    char* w = (char*)d_ws;
    int*      cnt   = (int*)     (w + 0);          //    40,000 B (reserve 64 KB)
    ushort_t* esrc2 = (ushort_t*)(w + 65536);      // 2,560,000 B
    ushort_t* xb    = (ushort_t*)(w + 2625536);    // 2,560,000 B
    ushort_t* Pb    = (ushort_t*)(w + 5185536);    // 2,560,000 B
    ushort_t* w1t   = (ushort_t*)(w + 7745536);    //   131,072 B
    ushort_t* w2tl  = (ushort_t*)(w + 7876608);    //    65,536 B
    ushort_t* w2tr  = (ushort_t*)(w + 7942144);    //    65,536 B
    float*    Rf    = (float*)   (w + 8007680);    // 5,120,000 B -> ends 13,127,680

    hipMemsetAsync(cnt, 0, N_NODES * sizeof(int), stream);

    bin_prep<<<BIN_BLOCKS + PREP_BLOCKS, K1_THREADS, 0, stream>>>(
        x, ei, W1_l, W1_r, W2_l, W2_r, xb, w1t, w2tl, w2tr, cnt, esrc2);
    gather_gemm<<<625, 512, 0, stream>>>(xb, cnt, esrc2, w1t, b1, w2tl, w2tr, Pb, Rf);
    gather_final<<<N_NODES, 64, 0, stream>>>(Pb, cnt, esrc2, Rf, b2, out);
}